// Round 13
// baseline (121.643 us; speedup 1.0000x reference)
//
#include <hip/hip_runtime.h>

// ---------------------------------------------------------------------------
// Head: out = softmax(mask((x@Wq)(x@Wk)^T * C^-0.5)) @ (x@Wv)
// B=4 T=4096 C=2048 H=128, fp32 in/out. bf16 MFMA pipeline.
//
// ws layout (bytes):
//   [0)        WT  bf16 [3][128][2048]   (W^T, Wq pre-scaled by C^-0.5)
//   [1572864)  Q   bf16 [16384][128]
//   [5767168)  K   bf16 [16384][128]
//   [9961472)  VT  bf16 [4][128][4096]   (V transposed per batch)
// ---------------------------------------------------------------------------

typedef __attribute__((ext_vector_type(8))) short s8v;   // 8 x bf16 (16B)
typedef __attribute__((ext_vector_type(4))) float f4v;   // MFMA acc frag

__device__ __forceinline__ unsigned short f2bf(float f) {
  unsigned int b = __float_as_uint(f);
  b += 0x7FFFu + ((b >> 16) & 1u);          // round-to-nearest-even
  return (unsigned short)(b >> 16);
}
__device__ __forceinline__ unsigned int pk2bf(float lo, float hi) {
  return (unsigned int)f2bf(lo) | ((unsigned int)f2bf(hi) << 16);
}

#define SCALE_QK 0.02209708691207961f       // 2048^-0.5

// ---- prep: WT[m][h][c] = Wm[c][h] (bf16); m=0 (q) pre-scaled --------------
__global__ void prep_wt(const float* __restrict__ Wq, const float* __restrict__ Wk,
                        const float* __restrict__ Wv, unsigned short* __restrict__ WT) {
  int e = blockIdx.x * 256 + threadIdx.x;   // < 3*262144
  int m = e >> 18;
  int r = e & 262143;                       // r = c*128 + h
  int c = r >> 7, h = r & 127;
  const float* W = (m == 0) ? Wq : (m == 1) ? Wk : Wv;
  float v = W[r];
  if (m == 0) v *= SCALE_QK;
  WT[m * 262144 + h * 2048 + c] = f2bf(v);
}

// ---- projection (unchanged from R12): 64 rows x 384 cols, 8 waves, BK=64 --
// Counted-vmcnt pipeline with DMA-order pin; timed ~61us.
__global__ __launch_bounds__(512, 1) void proj_kernel(
    const float* __restrict__ x, const unsigned short* __restrict__ WT,
    unsigned short* __restrict__ Qo, unsigned short* __restrict__ Ko,
    unsigned short* __restrict__ VTo)
{
  __shared__ __align__(16) char psmem[116736];
  // B0 @0 (48KB), B1 @49152, A0 @98304 (9216B), A1 @107520
  // epilogue scr [128][72] bf16 aliases @0 (B0; t31 reads only B1/A1)
  unsigned short* scr = (unsigned short*)psmem;

  const int tid = threadIdx.x;
  const int w = tid >> 6, lane = tid & 63;
  const int l15 = lane & 15, g = lane >> 4;
  const int wr = w >> 2, wc = w & 3;
  const int rowbase = blockIdx.x * 64;

  f4v acc[12];
  #pragma unroll
  for (int n = 0; n < 12; ++n) acc[n] = (f4v){0.f, 0.f, 0.f, 0.f};

  const int arow = tid >> 3;                 // 0..63
  const int akc  = (tid & 7) * 16;           // byte chunk within A row
  const float* xsrc = x + (size_t)(rowbase + arow) * 2048 + (tid & 7) * 8;
  const char* WTb = (const char*)WT;

#define STAGE_B(dst_, k0_)                                                     \
  {                                                                            \
    _Pragma("unroll")                                                          \
    for (int p = 0; p < 6; ++p) {                                              \
      const int off = tid * 16 + p * 8192;                                     \
      const int row = off >> 7, chunk = off & 127;                             \
      __builtin_amdgcn_global_load_lds(                                        \
        (const __attribute__((address_space(1))) void*)(                       \
            WTb + (size_t)row * 4096 + (size_t)(k0_) * 2 +                     \
            (chunk ^ ((row & 7) << 4))),                                       \
        (__attribute__((address_space(3))) void*)((dst_) + off), 16, 0, 0);    \
    }                                                                          \
  }

#define WRITE_A(dst_, aa_, ab_)                                                \
  {                                                                            \
    s8v t_;                                                                    \
    _Pragma("unroll")                                                          \
    for (int i = 0; i < 4; ++i) { t_[i] = (short)f2bf(aa_[i]);                 \
                                  t_[i + 4] = (short)f2bf(ab_[i]); }           \
    *(s8v*)((dst_) + arow * 144 + akc) = t_;                                   \
  }

#define COMPUTE(SEL)                                                           \
  {                                                                            \
    const char* Bb = psmem + (SEL) * 49152;                                    \
    const char* Ab = psmem + 98304 + (SEL) * 9216;                             \
    s8v af[2][2], bfr[6][2];                                                   \
    _Pragma("unroll")                                                          \
    for (int mi = 0; mi < 2; ++mi)                                             \
      _Pragma("unroll")                                                        \
      for (int kk = 0; kk < 2; ++kk)                                           \
        af[mi][kk] = *(const s8v*)(Ab + (32 * wr + 16 * mi + l15) * 144 +      \
                                   kk * 64 + g * 16);                          \
    _Pragma("unroll")                                                          \
    for (int nl = 0; nl < 6; ++nl) {                                           \
      const int row = 96 * wc + 16 * nl + l15;                                 \
      _Pragma("unroll")                                                        \
      for (int kk = 0; kk < 2; ++kk)                                           \
        bfr[nl][kk] = *(const s8v*)(Bb + row * 128 +                           \
                       ((kk * 64 + g * 16) ^ ((l15 & 7) << 4)));               \
    }                                                                          \
    __builtin_amdgcn_s_setprio(1);                                             \
    _Pragma("unroll")                                                          \
    for (int kk = 0; kk < 2; ++kk)                                             \
      _Pragma("unroll")                                                        \
      for (int mi = 0; mi < 2; ++mi)                                           \
        _Pragma("unroll")                                                      \
        for (int nl = 0; nl < 6; ++nl)                                         \
          acc[mi * 6 + nl] = __builtin_amdgcn_mfma_f32_16x16x32_bf16(          \
              af[mi][kk], bfr[nl][kk], acc[mi * 6 + nl], 0, 0, 0);             \
    __builtin_amdgcn_s_setprio(0);                                             \
  }

#define PBODY(SEL, K0, XA, XB, DOX, WN)                                        \
  {                                                                            \
    if ((K0) + 64 < 2048) {                                                    \
      STAGE_B(psmem + ((SEL) ^ 1) * 49152, (K0) + 64)                          \
    }                                                                          \
    __builtin_amdgcn_sched_barrier(0);   /* DMAs strictly oldest */            \
    if ((K0) + 64 < 2048) {                                                    \
      WRITE_A(psmem + 98304 + ((SEL) ^ 1) * 9216, XA, XB)                      \
    }                                                                          \
    if (DOX) {                                                                 \
      XA = *(const f4v*)(xsrc + (K0) + 192);                                   \
      XB = *(const f4v*)(xsrc + (K0) + 196);                                   \
    }                                                                          \
    COMPUTE(SEL)                                                               \
    asm volatile("s_waitcnt lgkmcnt(0)" ::: "memory");                         \
    asm volatile("s_waitcnt vmcnt(" #WN ")" ::: "memory");                     \
    __builtin_amdgcn_s_barrier();                                              \
    __builtin_amdgcn_sched_barrier(0);                                         \
  }

  // prologue: x(0); B(0) [PIN]; x(1); A(0)<-x(0); issue x(2); wait B(0)
  f4v xe_a = *(const f4v*)(xsrc);
  f4v xe_b = *(const f4v*)(xsrc + 4);
  STAGE_B(psmem, 0)
  __builtin_amdgcn_sched_barrier(0);
  f4v xo_a = *(const f4v*)(xsrc + 64);
  f4v xo_b = *(const f4v*)(xsrc + 68);
  WRITE_A(psmem + 98304, xe_a, xe_b)
  xe_a = *(const f4v*)(xsrc + 128);
  xe_b = *(const f4v*)(xsrc + 132);
  asm volatile("s_waitcnt lgkmcnt(0)" ::: "memory");
  asm volatile("s_waitcnt vmcnt(4)" ::: "memory");   // B(0) done; x(1),x(2) fly
  __builtin_amdgcn_s_barrier();
  __builtin_amdgcn_sched_barrier(0);

  for (int it = 0; it < 14; ++it) {                  // bodies 0..27 (all full)
    const int k0 = it * 128;
    PBODY(0, k0, xo_a, xo_b, 1, 2)
    PBODY(1, k0 + 64, xe_a, xe_b, 1, 2)
  }
  PBODY(0, 1792, xo_a, xo_b, 1, 2)                   // t28 (loads x31)
  PBODY(1, 1856, xe_a, xe_b, 0, 0)                   // t29
  PBODY(0, 1920, xo_a, xo_b, 0, 0)                   // t30 (stages B31,A31)
  COMPUTE(1)                                         // t31
#undef PBODY
#undef STAGE_B
#undef WRITE_A
#undef COMPUTE

  // ---- epilogue: q,k direct; v -> LDS transpose (scr aliases B0) ----
  #pragma unroll
  for (int mi = 0; mi < 2; ++mi) {
    #pragma unroll
    for (int nl = 0; nl < 6; ++nl) {
      const int colg = 96 * wc + 16 * nl + l15;   // 0..383
      const int m = colg >> 7;                    // 0=q 1=k 2=v
      const int h = colg & 127;
      const f4v a = acc[mi * 6 + nl];
      if (m < 2) {
        unsigned short* dst = (m == 0) ? Qo : Ko;
        #pragma unroll
        for (int r = 0; r < 4; ++r) {
          const int t = rowbase + 32 * wr + 16 * mi + 4 * g + r;
          dst[(size_t)t * 128 + h] = f2bf(a[r]);
        }
      } else {
        #pragma unroll
        for (int r = 0; r < 4; ++r) {
          const int tl = 32 * wr + 16 * mi + 4 * g + r;  // 0..63
          scr[h * 72 + tl] = f2bf(a[r]);
        }
      }
    }
  }
  __syncthreads();
  {
    const int b   = rowbase >> 12;
    const int tg0 = rowbase & 4095;
    const int h    = tid >> 2;                    // 0..127
    const int toff = (tid & 3) * 16;              // 0..48
    unsigned short* dst = VTo + (size_t)(b * 128 + h) * 4096 + tg0 + toff;
    *(s8v*)(dst)     = *(const s8v*)(&scr[h * 72 + toff]);
    *(s8v*)(dst + 8) = *(const s8v*)(&scr[h * 72 + toff + 8]);
  }
}

// ---- attention ------------------------------------------------------------
// R12 loop body; strip mapping REVERTED to R6's LPT (descending s, batch =
// bid&3). Cross-round accounting (R6/R7 vs R9/R10/R11) shows the R8 remap
// cost ~27us; R6 mapping measured ~2x faster for this kernel.
__global__ __launch_bounds__(256, 2) void attn_kernel(
    const unsigned short* __restrict__ Q, const unsigned short* __restrict__ K,
    const unsigned short* __restrict__ VT, float* __restrict__ out)
{
  __shared__ __align__(16) char smem[71168];
  // [0)      KV dbuf: buf c at c*32768: K 16KB, V 16KB  (aliased by o merge)
  // [65536)  plds [4][16*40] bf16   [70656) ml [4][16][2] f32
  unsigned short* plds = (unsigned short*)(smem + 65536);
  float* mlp = (float*)(smem + 70656);

  const int tid  = threadIdx.x;
  const int w    = tid >> 6;
  const int lane = tid & 63;
  const int l15 = lane & 15, g = lane >> 4;

  const int bid = blockIdx.x;
  const int s   = 127 - (bid >> 2);              // LPT: longest strips first
  const int b   = bid & 3;                       // batch <-> XCD affinity
  const int qb = s * 32;
  const int roff = (w >> 1) * 16, half = w & 1;
  const int ntiles = (qb + 95) >> 6;

  const char* Kg = (const char*)(K  + (size_t)b * 4096 * 128);
  const char* Vg = (const char*)(VT + (size_t)b * 128 * 4096);
  const unsigned short* Qb = Q + (size_t)b * 4096 * 128;

  s8v qf[4];
  #pragma unroll
  for (int kk = 0; kk < 4; ++kk)
    qf[kk] = *(const s8v*)(Qb + (size_t)(qb + roff + l15) * 128 + kk * 32 + g * 8);

  f4v o[8];
  #pragma unroll
  for (int n = 0; n < 8; ++n) o[n] = (f4v){0.f, 0.f, 0.f, 0.f};
  float mrun = -1e30f, lrun = 0.f;               // per-lane: q-row = l15

  const int off0 = tid * 16;                     // staging: 16B per thread

#define STAGE(Kl_, kvb_)                                                       \
  {                                                                            \
    char* Kl = (Kl_);                                                          \
    _Pragma("unroll")                                                          \
    for (int p = 0; p < 4; ++p) {                                              \
      const int off = off0 + p * 4096;                                         \
      const int ks = off ^ (((off >> 8) & 7) << 4);                            \
      __builtin_amdgcn_global_load_lds(                                        \
        (const __attribute__((address_space(1))) void*)(Kg + (size_t)(kvb_) * 256 + ks), \
        (__attribute__((address_space(3))) void*)(Kl + off), 16, 0, 0);        \
    }                                                                          \
    _Pragma("unroll")                                                          \
    for (int p = 0; p < 4; ++p) {                                              \
      const int off = off0 + p * 4096;                                         \
      const int h = off >> 7;                                                  \
      const int cs = (off & 127) ^ ((h & 7) << 4);                             \
      __builtin_amdgcn_global_load_lds(                                        \
        (const __attribute__((address_space(1))) void*)(Vg + (size_t)h * 8192 + (size_t)(kvb_) * 2 + cs), \
        (__attribute__((address_space(3))) void*)(Kl + 16384 + off), 16, 0, 0); \
    }                                                                          \
  }

  STAGE(smem, 0)
  __syncthreads();                               // drain tile-0 DMA once

  int cur = 0;
  for (int it = 0; it < ntiles; ++it) {
    const int kvb = it * 64;
    // issue tile t+1, then await tile t (oldest 8) — 2 tiles in flight
    if (it + 1 < ntiles) {
      STAGE(smem + (cur ^ 1) * 32768, kvb + 64)
      __builtin_amdgcn_sched_barrier(0);         // pin: DMAs in issue order
      asm volatile("s_waitcnt vmcnt(8)" ::: "memory");
    } else {
      asm volatile("s_waitcnt vmcnt(0)" ::: "memory");
    }
    __builtin_amdgcn_s_barrier();                // bar1: tile t visible to all
    __builtin_amdgcn_sched_barrier(0);

    const char* Kl = smem + cur * 32768;
    const char* Vl = Kl + 16384;
    s8v kf[2][4];
    #pragma unroll
    for (int t2 = 0; t2 < 2; ++t2) {
      const int row = half * 32 + t2 * 16 + l15;
      #pragma unroll
      for (int kk = 0; kk < 4; ++kk)
        kf[t2][kk] = *(const s8v*)(Kl + ((row * 256 + kk * 64 + g * 16) ^ ((l15 & 7) << 4)));
    }
    s8v vf[8];
    #pragma unroll
    for (int n = 0; n < 8; ++n) {
      const int row = n * 16 + l15;
      vf[n] = *(const s8v*)(Vl + ((row * 128 + half * 64 + g * 16) ^ ((l15 & 7) << 4)));
    }
    // QK^T swapped: lane holds q-row l15, kv-local = 16*t2 + 4*g + r
    f4v sc[2];
    sc[0] = (f4v){0.f, 0.f, 0.f, 0.f};
    sc[1] = (f4v){0.f, 0.f, 0.f, 0.f};
    __builtin_amdgcn_s_setprio(1);
    #pragma unroll
    for (int kk = 0; kk < 4; ++kk) {
      sc[0] = __builtin_amdgcn_mfma_f32_16x16x32_bf16(kf[0][kk], qf[kk], sc[0], 0, 0, 0);
      sc[1] = __builtin_amdgcn_mfma_f32_16x16x32_bf16(kf[1][kk], qf[kk], sc[1], 0, 0, 0);
    }
    __builtin_amdgcn_s_setprio(0);
    // causal mask (diagonal tile only)
    if (it == ntiles - 1) {
      const int qrow = qb + roff + l15;
      #pragma unroll
      for (int t2 = 0; t2 < 2; ++t2)
        #pragma unroll
        for (int r = 0; r < 4; ++r) {
          const int kv = kvb + half * 32 + 16 * t2 + 4 * g + r;
          if (kv > qrow) sc[t2][r] = -1e30f;
        }
    }
    // lane-local online softmax (row = l15; partners at lane^16, lane^32)
    float v = fmaxf(fmaxf(fmaxf(sc[0][0], sc[0][1]), fmaxf(sc[0][2], sc[0][3])),
                    fmaxf(fmaxf(sc[1][0], sc[1][1]), fmaxf(sc[1][2], sc[1][3])));
    v = fmaxf(v, __shfl_xor(v, 16));
    v = fmaxf(v, __shfl_xor(v, 32));
    if (__any(v > mrun + 4.0f)) {                // defer-max (T13)
      const float mnew = fmaxf(mrun, v);
      const float corr = __expf(mrun - mnew);
      mrun = mnew;
      lrun *= corr;
      #pragma unroll
      for (int n = 0; n < 8; ++n)
        #pragma unroll
        for (int r = 0; r < 4; ++r) o[n][r] *= corr;
    }
    f4v p0, p1;
    #pragma unroll
    for (int r = 0; r < 4; ++r) {
      p0[r] = __expf(sc[0][r] - mrun);
      p1[r] = __expf(sc[1][r] - mrun);
    }
    lrun += (p0[0] + p0[1]) + (p0[2] + p0[3]) + (p1[0] + p1[1]) + (p1[2] + p1[3]);
    // P bounce: 4 packed u32 stores -> one b128 A/B-frag read (per-wave buf)
    unsigned short* pw = plds + w * 640;
    *(unsigned int*)(&pw[l15 * 40 + 4 * g])          = pk2bf(p0[0], p0[1]);
    *(unsigned int*)(&pw[l15 * 40 + 4 * g + 2])      = pk2bf(p0[2], p0[3]);
    *(unsigned int*)(&pw[l15 * 40 + 16 + 4 * g])     = pk2bf(p1[0], p1[1]);
    *(unsigned int*)(&pw[l15 * 40 + 16 + 4 * g + 2]) = pk2bf(p1[2], p1[3]);
    const s8v pf = *(const s8v*)(pw + l15 * 40 + g * 8);
    // PV swapped: O^T += VT_frag x P -> lane holds q=l15, h=16n+4g+r
    __builtin_amdgcn_s_setprio(1);
    #pragma unroll
    for (int n = 0; n < 8; ++n)
      o[n] = __builtin_amdgcn_mfma_f32_16x16x32_bf16(vf[n], pf, o[n], 0, 0, 0);
    __builtin_amdgcn_s_setprio(0);

    __builtin_amdgcn_s_barrier();                // bar2: reads done (WAR)
    __builtin_amdgcn_sched_barrier(0);
    cur ^= 1;
  }
#undef STAGE

  // ---- per-wave finish: l reduce (2 shuffles), dump {m,l,o} partials ----
  float lt = lrun;
  lt += __shfl_xor(lt, 16);
  lt += __shfl_xor(lt, 32);
  if (g == 0) {
    mlp[(w * 16 + l15) * 2 + 0] = mrun;
    mlp[(w * 16 + l15) * 2 + 1] = lt;
  }
  float* ol = (float*)smem;                      // [4][16][132] aliases KV bufs
  #pragma unroll
  for (int n = 0; n < 8; ++n)
    *(f4v*)(&ol[(w * 16 + l15) * 132 + 16 * n + 4 * g]) = o[n];
  __syncthreads();

  // ---- merge the 2 col-halves of each 16-row group ----
  {
    const int st  = tid >> 7;                    // row group 0/1
    const int t7  = tid & 127;
    const int row = t7 >> 3;                     // 0..15
    const int hb  = (t7 & 7) * 16;               // 0..112
    const int wA = 2 * st, wB = 2 * st + 1;
    const float m0 = mlp[(wA * 16 + row) * 2], l0 = mlp[(wA * 16 + row) * 2 + 1];
    const float m1 = mlp[(wB * 16 + row) * 2], l1 = mlp[(wB * 16 + row) * 2 + 1];
    const float M  = fmaxf(m0, m1);
    const float w0 = __expf(m0 - M), w1 = __expf(m1 - M);
    const float inv = 1.0f / (w0 * l0 + w1 * l1);
    float* dst = out + (size_t)(b * 4096 + qb + 16 * st + row) * 128 + hb;
    #pragma unroll
    for (int j4 = 0; j4 < 4; ++j4) {
      const f4v a = *(const f4v*)(&ol[(wA * 16 + row) * 132 + hb + 4 * j4]);
      const f4v c = *(const f4v*)(&ol[(wB * 16 + row) * 132 + hb + 4 * j4]);
      f4v res;
      #pragma unroll
      for (int jj = 0; jj < 4; ++jj) res[jj] = (w0 * a[jj] + w1 * c[jj]) * inv;
      *(f4v*)(dst + 4 * j4) = res;
    }
  }
}

extern "C" void kernel_launch(void* const* d_in, const int* in_sizes, int n_in,
                              void* d_out, int out_size, void* d_ws, size_t ws_size,
                              hipStream_t stream) {
  const float* x  = (const float*)d_in[0];
  const float* Wq = (const float*)d_in[1];
  const float* Wk = (const float*)d_in[2];
  const float* Wv = (const float*)d_in[3];

  unsigned short* WT = (unsigned short*)d_ws;
  unsigned short* Q  = (unsigned short*)((char*)d_ws + 1572864);
  unsigned short* K  = (unsigned short*)((char*)d_ws + 5767168);
  unsigned short* VT = (unsigned short*)((char*)d_ws + 9961472);
  float* out = (float*)d_out;

  prep_wt<<<3072, 256, 0, stream>>>(Wq, Wk, Wv, WT);
  proj_kernel<<<256, 512, 0, stream>>>(x, WT, Q, K, VT);
  attn_kernel<<<512, 256, 0, stream>>>(Q, K, VT, out);
}

// Round 14
// 121.461 us; speedup vs baseline: 1.0015x; 1.0015x over previous
//
#include <hip/hip_runtime.h>

// ---------------------------------------------------------------------------
// Head: out = softmax(mask((x@Wq)(x@Wk)^T * C^-0.5)) @ (x@Wv)
// B=4 T=4096 C=2048 H=128, fp32 in/out. bf16 MFMA pipeline.
//
// ws layout (bytes):
//   [0)        WT  bf16 [3][128][2048]   (W^T, Wq pre-scaled by C^-0.5)
//   [1572864)  Q   bf16 [16384][128]
//   [5767168)  K   bf16 [16384][128]
//   [9961472)  VT  bf16 [4][128][4096]   (V transposed per batch)
// ---------------------------------------------------------------------------

typedef __attribute__((ext_vector_type(8))) short s8v;   // 8 x bf16 (16B)
typedef __attribute__((ext_vector_type(4))) float f4v;   // MFMA acc frag

__device__ __forceinline__ unsigned short f2bf(float f) {
  unsigned int b = __float_as_uint(f);
  b += 0x7FFFu + ((b >> 16) & 1u);          // round-to-nearest-even
  return (unsigned short)(b >> 16);
}
__device__ __forceinline__ unsigned int pk2bf(float lo, float hi) {
  return (unsigned int)f2bf(lo) | ((unsigned int)f2bf(hi) << 16);
}

#define SCALE_QK 0.02209708691207961f       // 2048^-0.5

// ---- prep: WT[m][h][c] = Wm[c][h] (bf16); m=0 (q) pre-scaled --------------
__global__ void prep_wt(const float* __restrict__ Wq, const float* __restrict__ Wk,
                        const float* __restrict__ Wv, unsigned short* __restrict__ WT) {
  int e = blockIdx.x * 256 + threadIdx.x;   // < 3*262144
  int m = e >> 18;
  int r = e & 262143;                       // r = c*128 + h
  int c = r >> 7, h = r & 127;
  const float* W = (m == 0) ? Wq : (m == 1) ? Wk : Wv;
  float v = W[r];
  if (m == 0) v *= SCALE_QK;
  WT[m * 262144 + h * 2048 + c] = f2bf(v);
}

// ---- projection (unchanged from R12/R13, ~43us): 64x384, 8 waves, BK=64 ---
// Counted-vmcnt pipeline with DMA-order pin.
__global__ __launch_bounds__(512, 1) void proj_kernel(
    const float* __restrict__ x, const unsigned short* __restrict__ WT,
    unsigned short* __restrict__ Qo, unsigned short* __restrict__ Ko,
    unsigned short* __restrict__ VTo)
{
  __shared__ __align__(16) char psmem[116736];
  // B0 @0 (48KB), B1 @49152, A0 @98304 (9216B), A1 @107520
  // epilogue scr [128][72] bf16 aliases @0 (B0; t31 reads only B1/A1)
  unsigned short* scr = (unsigned short*)psmem;

  const int tid = threadIdx.x;
  const int w = tid >> 6, lane = tid & 63;
  const int l15 = lane & 15, g = lane >> 4;
  const int wr = w >> 2, wc = w & 3;
  const int rowbase = blockIdx.x * 64;

  f4v acc[12];
  #pragma unroll
  for (int n = 0; n < 12; ++n) acc[n] = (f4v){0.f, 0.f, 0.f, 0.f};

  const int arow = tid >> 3;                 // 0..63
  const int akc  = (tid & 7) * 16;           // byte chunk within A row
  const float* xsrc = x + (size_t)(rowbase + arow) * 2048 + (tid & 7) * 8;
  const char* WTb = (const char*)WT;

#define STAGE_B(dst_, k0_)                                                     \
  {                                                                            \
    _Pragma("unroll")                                                          \
    for (int p = 0; p < 6; ++p) {                                              \
      const int off = tid * 16 + p * 8192;                                     \
      const int row = off >> 7, chunk = off & 127;                             \
      __builtin_amdgcn_global_load_lds(                                        \
        (const __attribute__((address_space(1))) void*)(                       \
            WTb + (size_t)row * 4096 + (size_t)(k0_) * 2 +                     \
            (chunk ^ ((row & 7) << 4))),                                       \
        (__attribute__((address_space(3))) void*)((dst_) + off), 16, 0, 0);    \
    }                                                                          \
  }

#define WRITE_A(dst_, aa_, ab_)                                                \
  {                                                                            \
    s8v t_;                                                                    \
    _Pragma("unroll")                                                          \
    for (int i = 0; i < 4; ++i) { t_[i] = (short)f2bf(aa_[i]);                 \
                                  t_[i + 4] = (short)f2bf(ab_[i]); }           \
    *(s8v*)((dst_) + arow * 144 + akc) = t_;                                   \
  }

#define COMPUTE(SEL)                                                           \
  {                                                                            \
    const char* Bb = psmem + (SEL) * 49152;                                    \
    const char* Ab = psmem + 98304 + (SEL) * 9216;                             \
    s8v af[2][2], bfr[6][2];                                                   \
    _Pragma("unroll")                                                          \
    for (int mi = 0; mi < 2; ++mi)                                             \
      _Pragma("unroll")                                                        \
      for (int kk = 0; kk < 2; ++kk)                                           \
        af[mi][kk] = *(const s8v*)(Ab + (32 * wr + 16 * mi + l15) * 144 +      \
                                   kk * 64 + g * 16);                          \
    _Pragma("unroll")                                                          \
    for (int nl = 0; nl < 6; ++nl) {                                           \
      const int row = 96 * wc + 16 * nl + l15;                                 \
      _Pragma("unroll")                                                        \
      for (int kk = 0; kk < 2; ++kk)                                           \
        bfr[nl][kk] = *(const s8v*)(Bb + row * 128 +                           \
                       ((kk * 64 + g * 16) ^ ((l15 & 7) << 4)));               \
    }                                                                          \
    __builtin_amdgcn_s_setprio(1);                                             \
    _Pragma("unroll")                                                          \
    for (int kk = 0; kk < 2; ++kk)                                             \
      _Pragma("unroll")                                                        \
      for (int mi = 0; mi < 2; ++mi)                                           \
        _Pragma("unroll")                                                      \
        for (int nl = 0; nl < 6; ++nl)                                         \
          acc[mi * 6 + nl] = __builtin_amdgcn_mfma_f32_16x16x32_bf16(          \
              af[mi][kk], bfr[nl][kk], acc[mi * 6 + nl], 0, 0, 0);             \
    __builtin_amdgcn_s_setprio(0);                                             \
  }

#define PBODY(SEL, K0, XA, XB, DOX, WN)                                        \
  {                                                                            \
    if ((K0) + 64 < 2048) {                                                    \
      STAGE_B(psmem + ((SEL) ^ 1) * 49152, (K0) + 64)                          \
    }                                                                          \
    __builtin_amdgcn_sched_barrier(0);   /* DMAs strictly oldest */            \
    if ((K0) + 64 < 2048) {                                                    \
      WRITE_A(psmem + 98304 + ((SEL) ^ 1) * 9216, XA, XB)                      \
    }                                                                          \
    if (DOX) {                                                                 \
      XA = *(const f4v*)(xsrc + (K0) + 192);                                   \
      XB = *(const f4v*)(xsrc + (K0) + 196);                                   \
    }                                                                          \
    COMPUTE(SEL)                                                               \
    asm volatile("s_waitcnt lgkmcnt(0)" ::: "memory");                         \
    asm volatile("s_waitcnt vmcnt(" #WN ")" ::: "memory");                     \
    __builtin_amdgcn_s_barrier();                                              \
    __builtin_amdgcn_sched_barrier(0);                                         \
  }

  // prologue: x(0); B(0) [PIN]; x(1); A(0)<-x(0); issue x(2); wait B(0)
  f4v xe_a = *(const f4v*)(xsrc);
  f4v xe_b = *(const f4v*)(xsrc + 4);
  STAGE_B(psmem, 0)
  __builtin_amdgcn_sched_barrier(0);
  f4v xo_a = *(const f4v*)(xsrc + 64);
  f4v xo_b = *(const f4v*)(xsrc + 68);
  WRITE_A(psmem + 98304, xe_a, xe_b)
  xe_a = *(const f4v*)(xsrc + 128);
  xe_b = *(const f4v*)(xsrc + 132);
  asm volatile("s_waitcnt lgkmcnt(0)" ::: "memory");
  asm volatile("s_waitcnt vmcnt(4)" ::: "memory");   // B(0) done; x(1),x(2) fly
  __builtin_amdgcn_s_barrier();
  __builtin_amdgcn_sched_barrier(0);

  for (int it = 0; it < 14; ++it) {                  // bodies 0..27 (all full)
    const int k0 = it * 128;
    PBODY(0, k0, xo_a, xo_b, 1, 2)
    PBODY(1, k0 + 64, xe_a, xe_b, 1, 2)
  }
  PBODY(0, 1792, xo_a, xo_b, 1, 2)                   // t28 (loads x31)
  PBODY(1, 1856, xe_a, xe_b, 0, 0)                   // t29
  PBODY(0, 1920, xo_a, xo_b, 0, 0)                   // t30 (stages B31,A31)
  COMPUTE(1)                                         // t31
#undef PBODY
#undef STAGE_B
#undef WRITE_A
#undef COMPUTE

  // ---- epilogue: q,k direct; v -> LDS transpose (scr aliases B0) ----
  #pragma unroll
  for (int mi = 0; mi < 2; ++mi) {
    #pragma unroll
    for (int nl = 0; nl < 6; ++nl) {
      const int colg = 96 * wc + 16 * nl + l15;   // 0..383
      const int m = colg >> 7;                    // 0=q 1=k 2=v
      const int h = colg & 127;
      const f4v a = acc[mi * 6 + nl];
      if (m < 2) {
        unsigned short* dst = (m == 0) ? Qo : Ko;
        #pragma unroll
        for (int r = 0; r < 4; ++r) {
          const int t = rowbase + 32 * wr + 16 * mi + 4 * g + r;
          dst[(size_t)t * 128 + h] = f2bf(a[r]);
        }
      } else {
        #pragma unroll
        for (int r = 0; r < 4; ++r) {
          const int tl = 32 * wr + 16 * mi + 4 * g + r;  // 0..63
          scr[h * 72 + tl] = f2bf(a[r]);
        }
      }
    }
  }
  __syncthreads();
  {
    const int b   = rowbase >> 12;
    const int tg0 = rowbase & 4095;
    const int h    = tid >> 2;                    // 0..127
    const int toff = (tid & 3) * 16;              // 0..48
    unsigned short* dst = VTo + (size_t)(b * 128 + h) * 4096 + tg0 + toff;
    *(s8v*)(dst)     = *(const s8v*)(&scr[h * 72 + toff]);
    *(s8v*)(dst + 8) = *(const s8v*)(&scr[h * 72 + toff + 8]);
  }
}

// ---- attention (VERBATIM R6 revert — best measured ~21us) ------------------
// Block = 4 waves, ONE 32-row q-strip; KV tile 64 DMA-staged to LDS (dbuf,
// XOR-swizzled via pre-swizzled source). SWAPPED MFMA: S^T=mfma(K,Q),
// O^T=mfma(VT,P) -> lane-local softmax. Simple __syncthreads() loop (NO
// sched_barrier pins — lets the compiler software-pipeline across iters;
// R12/R13's pinned counted-vmcnt loop measured 66-76us vs this at ~21).
__global__ __launch_bounds__(256, 2) void attn_kernel(
    const unsigned short* __restrict__ Q, const unsigned short* __restrict__ K,
    const unsigned short* __restrict__ VT, float* __restrict__ out)
{
  __shared__ __align__(16) char smem[71168];
  // [0)      KV dbuf: buf c at c*32768: K 16KB, V 16KB  (aliased by o merge)
  // [65536)  plds [4][16*40] bf16   [70656) ml [4][16][2] f32
  unsigned short* plds = (unsigned short*)(smem + 65536);
  float* mlp = (float*)(smem + 70656);

  const int tid  = threadIdx.x;
  const int w    = tid >> 6;
  const int lane = tid & 63;
  const int l15 = lane & 15, g = lane >> 4;

  const int b  = blockIdx.x & 3;                 // batch <-> XCD affinity
  const int s  = 127 - (blockIdx.x >> 2);        // LPT: longest strips first
  const int qb = s * 32;
  const int roff = (w >> 1) * 16, half = w & 1;
  const int ntiles = (qb + 95) >> 6;

  const char* Kg = (const char*)(K  + (size_t)b * 4096 * 128);
  const char* Vg = (const char*)(VT + (size_t)b * 128 * 4096);
  const unsigned short* Qb = Q + (size_t)b * 4096 * 128;

  s8v qf[4];
  #pragma unroll
  for (int kk = 0; kk < 4; ++kk)
    qf[kk] = *(const s8v*)(Qb + (size_t)(qb + roff + l15) * 128 + kk * 32 + g * 8);

  f4v o[8];
  #pragma unroll
  for (int n = 0; n < 8; ++n) o[n] = (f4v){0.f, 0.f, 0.f, 0.f};
  float mrun = -1e30f, lrun = 0.f;               // per-lane: q-row = l15

  const int off0 = tid * 16;                     // staging: 16B per thread

#define STAGE(Kl_, kvb_)                                                       \
  {                                                                            \
    char* Kl = (Kl_);                                                          \
    _Pragma("unroll")                                                          \
    for (int p = 0; p < 4; ++p) {                                              \
      const int off = off0 + p * 4096;                                         \
      const int ks = off ^ (((off >> 8) & 7) << 4);                            \
      __builtin_amdgcn_global_load_lds(                                        \
        (const __attribute__((address_space(1))) void*)(Kg + (size_t)(kvb_) * 256 + ks), \
        (__attribute__((address_space(3))) void*)(Kl + off), 16, 0, 0);        \
    }                                                                          \
    _Pragma("unroll")                                                          \
    for (int p = 0; p < 4; ++p) {                                              \
      const int off = off0 + p * 4096;                                         \
      const int h = off >> 7;                                                  \
      const int cs = (off & 127) ^ ((h & 7) << 4);                             \
      __builtin_amdgcn_global_load_lds(                                        \
        (const __attribute__((address_space(1))) void*)(Vg + (size_t)h * 8192 + (size_t)(kvb_) * 2 + cs), \
        (__attribute__((address_space(3))) void*)(Kl + 16384 + off), 16, 0, 0); \
    }                                                                          \
  }

  STAGE(smem, 0)
  __syncthreads();

  int cur = 0;
  for (int it = 0; it < ntiles; ++it) {
    const int kvb = it * 64;
    if (it + 1 < ntiles) STAGE(smem + (cur ^ 1) * 32768, kvb + 64)

    const char* Kl = smem + cur * 32768;
    const char* Vl = Kl + 16384;
    s8v kf[2][4];
    #pragma unroll
    for (int t2 = 0; t2 < 2; ++t2) {
      const int row = half * 32 + t2 * 16 + l15;
      #pragma unroll
      for (int kk = 0; kk < 4; ++kk)
        kf[t2][kk] = *(const s8v*)(Kl + ((row * 256 + kk * 64 + g * 16) ^ ((l15 & 7) << 4)));
    }
    s8v vf[8];
    #pragma unroll
    for (int n = 0; n < 8; ++n) {
      const int row = n * 16 + l15;
      vf[n] = *(const s8v*)(Vl + ((row * 128 + half * 64 + g * 16) ^ ((l15 & 7) << 4)));
    }
    // QK^T swapped: lane holds q-row l15, kv-local = 16*t2 + 4*g + r
    f4v sc[2];
    sc[0] = (f4v){0.f, 0.f, 0.f, 0.f};
    sc[1] = (f4v){0.f, 0.f, 0.f, 0.f};
    __builtin_amdgcn_s_setprio(1);
    #pragma unroll
    for (int kk = 0; kk < 4; ++kk) {
      sc[0] = __builtin_amdgcn_mfma_f32_16x16x32_bf16(kf[0][kk], qf[kk], sc[0], 0, 0, 0);
      sc[1] = __builtin_amdgcn_mfma_f32_16x16x32_bf16(kf[1][kk], qf[kk], sc[1], 0, 0, 0);
    }
    __builtin_amdgcn_s_setprio(0);
    // causal mask (diagonal tile only)
    if (it == ntiles - 1) {
      const int qrow = qb + roff + l15;
      #pragma unroll
      for (int t2 = 0; t2 < 2; ++t2)
        #pragma unroll
        for (int r = 0; r < 4; ++r) {
          const int kv = kvb + half * 32 + 16 * t2 + 4 * g + r;
          if (kv > qrow) sc[t2][r] = -1e30f;
        }
    }
    // lane-local online softmax (row = l15; partners at lane^16, lane^32)
    float v = fmaxf(fmaxf(fmaxf(sc[0][0], sc[0][1]), fmaxf(sc[0][2], sc[0][3])),
                    fmaxf(fmaxf(sc[1][0], sc[1][1]), fmaxf(sc[1][2], sc[1][3])));
    v = fmaxf(v, __shfl_xor(v, 16));
    v = fmaxf(v, __shfl_xor(v, 32));
    if (__any(v > mrun + 4.0f)) {                // defer-max (T13)
      const float mnew = fmaxf(mrun, v);
      const float corr = __expf(mrun - mnew);
      mrun = mnew;
      lrun *= corr;
      #pragma unroll
      for (int n = 0; n < 8; ++n)
        #pragma unroll
        for (int r = 0; r < 4; ++r) o[n][r] *= corr;
    }
    f4v p0, p1;
    #pragma unroll
    for (int r = 0; r < 4; ++r) {
      p0[r] = __expf(sc[0][r] - mrun);
      p1[r] = __expf(sc[1][r] - mrun);
    }
    lrun += (p0[0] + p0[1]) + (p0[2] + p0[3]) + (p1[0] + p1[1]) + (p1[2] + p1[3]);
    // P bounce: 4 packed u32 stores -> one b128 A/B-frag read (per-wave buf)
    unsigned short* pw = plds + w * 640;
    *(unsigned int*)(&pw[l15 * 40 + 4 * g])          = pk2bf(p0[0], p0[1]);
    *(unsigned int*)(&pw[l15 * 40 + 4 * g + 2])      = pk2bf(p0[2], p0[3]);
    *(unsigned int*)(&pw[l15 * 40 + 16 + 4 * g])     = pk2bf(p1[0], p1[1]);
    *(unsigned int*)(&pw[l15 * 40 + 16 + 4 * g + 2]) = pk2bf(p1[2], p1[3]);
    const s8v pf = *(const s8v*)(pw + l15 * 40 + g * 8);
    // PV swapped: O^T += VT_frag x P -> lane holds q=l15, h=16n+4g+r
    __builtin_amdgcn_s_setprio(1);
    #pragma unroll
    for (int n = 0; n < 8; ++n)
      o[n] = __builtin_amdgcn_mfma_f32_16x16x32_bf16(vf[n], pf, o[n], 0, 0, 0);
    __builtin_amdgcn_s_setprio(0);

    __syncthreads();                             // drains staging DMA + syncs
    cur ^= 1;
  }
#undef STAGE

  // ---- per-wave finish: l reduce (2 shuffles), dump {m,l,o} partials ----
  float lt = lrun;
  lt += __shfl_xor(lt, 16);
  lt += __shfl_xor(lt, 32);
  if (g == 0) {
    mlp[(w * 16 + l15) * 2 + 0] = mrun;
    mlp[(w * 16 + l15) * 2 + 1] = lt;
  }
  float* ol = (float*)smem;                      // [4][16][132] aliases KV bufs
  #pragma unroll
  for (int n = 0; n < 8; ++n)
    *(f4v*)(&ol[(w * 16 + l15) * 132 + 16 * n + 4 * g]) = o[n];
  __syncthreads();

  // ---- merge the 2 col-halves of each 16-row group ----
  {
    const int st  = tid >> 7;                    // row group 0/1
    const int t7  = tid & 127;
    const int row = t7 >> 3;                     // 0..15
    const int hb  = (t7 & 7) * 16;               // 0..112
    const int wA = 2 * st, wB = 2 * st + 1;
    const float m0 = mlp[(wA * 16 + row) * 2], l0 = mlp[(wA * 16 + row) * 2 + 1];
    const float m1 = mlp[(wB * 16 + row) * 2], l1 = mlp[(wB * 16 + row) * 2 + 1];
    const float M  = fmaxf(m0, m1);
    const float w0 = __expf(m0 - M), w1 = __expf(m1 - M);
    const float inv = 1.0f / (w0 * l0 + w1 * l1);
    float* dst = out + (size_t)(b * 4096 + qb + 16 * st + row) * 128 + hb;
    #pragma unroll
    for (int j4 = 0; j4 < 4; ++j4) {
      const f4v a = *(const f4v*)(&ol[(wA * 16 + row) * 132 + hb + 4 * j4]);
      const f4v c = *(const f4v*)(&ol[(wB * 16 + row) * 132 + hb + 4 * j4]);
      f4v res;
      #pragma unroll
      for (int jj = 0; jj < 4; ++jj) res[jj] = (w0 * a[jj] + w1 * c[jj]) * inv;
      *(f4v*)(dst + 4 * j4) = res;
    }
  }
}

extern "C" void kernel_launch(void* const* d_in, const int* in_sizes, int n_in,
                              void* d_out, int out_size, void* d_ws, size_t ws_size,
                              hipStream_t stream) {
  const float* x  = (const float*)d_in[0];
  const float* Wq = (const float*)d_in[1];
  const float* Wk = (const float*)d_in[2];
  const float* Wv = (const float*)d_in[3];

  unsigned short* WT = (unsigned short*)d_ws;
  unsigned short* Q  = (unsigned short*)((char*)d_ws + 1572864);
  unsigned short* K  = (unsigned short*)((char*)d_ws + 5767168);
  unsigned short* VT = (unsigned short*)((char*)d_ws + 9961472);
  float* out = (float*)d_out;

  prep_wt<<<3072, 256, 0, stream>>>(Wq, Wk, Wv, WT);
  proj_kernel<<<256, 512, 0, stream>>>(x, WT, Q, K, VT);
  attn_kernel<<<512, 256, 0, stream>>>(Q, K, VT, out);
}

// Round 15
// 111.004 us; speedup vs baseline: 1.0958x; 1.0942x over previous
//
#include <hip/hip_runtime.h>

// ---------------------------------------------------------------------------
// Head: out = softmax(mask((x@Wq)(x@Wk)^T * C^-0.5)) @ (x@Wv)
// B=4 T=4096 C=2048 H=128, fp32 in/out. bf16 MFMA pipeline.
//
// ws layout (bytes):
//   [0)        WT  bf16 [3][128][2048]   (W^T, Wq pre-scaled by C^-0.5)
//   [1572864)  Q   bf16 [16384][128]
//   [5767168)  K   bf16 [16384][128]
//   [9961472)  VT  bf16 [4][128][4096]   (V transposed per batch)
// ---------------------------------------------------------------------------

typedef __attribute__((ext_vector_type(8))) short s8v;   // 8 x bf16 (16B)
typedef __attribute__((ext_vector_type(4))) float f4v;   // MFMA acc frag

__device__ __forceinline__ unsigned short f2bf(float f) {
  unsigned int b = __float_as_uint(f);
  b += 0x7FFFu + ((b >> 16) & 1u);          // round-to-nearest-even
  return (unsigned short)(b >> 16);
}
__device__ __forceinline__ unsigned int pk2bf(float lo, float hi) {
  return (unsigned int)f2bf(lo) | ((unsigned int)f2bf(hi) << 16);
}

#define SCALE_QK 0.02209708691207961f       // 2048^-0.5

// ---- prep: WT[m][h][c] = Wm[c][h] (bf16); m=0 (q) pre-scaled --------------
__global__ void prep_wt(const float* __restrict__ Wq, const float* __restrict__ Wk,
                        const float* __restrict__ Wv, unsigned short* __restrict__ WT) {
  int e = blockIdx.x * 256 + threadIdx.x;   // < 3*262144
  int m = e >> 18;
  int r = e & 262143;                       // r = c*128 + h
  int c = r >> 7, h = r & 127;
  const float* W = (m == 0) ? Wq : (m == 1) ? Wk : Wv;
  float v = W[r];
  if (m == 0) v *= SCALE_QK;
  WT[m * 262144 + h * 2048 + c] = f2bf(v);
}

// ---- projection (~43us): 64x384, 8 waves, BK=64, counted-vmcnt pipeline ---
// DMA-order pin kept (carries the vmcnt(2) contract); the TRAILING
// sched_barrier after s_barrier removed (m141-class cross-body pin; the
// "memory"-clobbered asm already fences all memory ops).
__global__ __launch_bounds__(512, 1) void proj_kernel(
    const float* __restrict__ x, const unsigned short* __restrict__ WT,
    unsigned short* __restrict__ Qo, unsigned short* __restrict__ Ko,
    unsigned short* __restrict__ VTo)
{
  __shared__ __align__(16) char psmem[116736];
  // B0 @0 (48KB), B1 @49152, A0 @98304 (9216B), A1 @107520
  // epilogue scr [128][72] bf16 aliases @0 (B0; t31 reads only B1/A1)
  unsigned short* scr = (unsigned short*)psmem;

  const int tid = threadIdx.x;
  const int w = tid >> 6, lane = tid & 63;
  const int l15 = lane & 15, g = lane >> 4;
  const int wr = w >> 2, wc = w & 3;
  const int rowbase = blockIdx.x * 64;

  f4v acc[12];
  #pragma unroll
  for (int n = 0; n < 12; ++n) acc[n] = (f4v){0.f, 0.f, 0.f, 0.f};

  const int arow = tid >> 3;                 // 0..63
  const int akc  = (tid & 7) * 16;           // byte chunk within A row
  const float* xsrc = x + (size_t)(rowbase + arow) * 2048 + (tid & 7) * 8;
  const char* WTb = (const char*)WT;

#define STAGE_B(dst_, k0_)                                                     \
  {                                                                            \
    _Pragma("unroll")                                                          \
    for (int p = 0; p < 6; ++p) {                                              \
      const int off = tid * 16 + p * 8192;                                     \
      const int row = off >> 7, chunk = off & 127;                             \
      __builtin_amdgcn_global_load_lds(                                        \
        (const __attribute__((address_space(1))) void*)(                       \
            WTb + (size_t)row * 4096 + (size_t)(k0_) * 2 +                     \
            (chunk ^ ((row & 7) << 4))),                                       \
        (__attribute__((address_space(3))) void*)((dst_) + off), 16, 0, 0);    \
    }                                                                          \
  }

#define WRITE_A(dst_, aa_, ab_)                                                \
  {                                                                            \
    s8v t_;                                                                    \
    _Pragma("unroll")                                                          \
    for (int i = 0; i < 4; ++i) { t_[i] = (short)f2bf(aa_[i]);                 \
                                  t_[i + 4] = (short)f2bf(ab_[i]); }           \
    *(s8v*)((dst_) + arow * 144 + akc) = t_;                                   \
  }

#define COMPUTE(SEL)                                                           \
  {                                                                            \
    const char* Bb = psmem + (SEL) * 49152;                                    \
    const char* Ab = psmem + 98304 + (SEL) * 9216;                             \
    s8v af[2][2], bfr[6][2];                                                   \
    _Pragma("unroll")                                                          \
    for (int mi = 0; mi < 2; ++mi)                                             \
      _Pragma("unroll")                                                        \
      for (int kk = 0; kk < 2; ++kk)                                           \
        af[mi][kk] = *(const s8v*)(Ab + (32 * wr + 16 * mi + l15) * 144 +      \
                                   kk * 64 + g * 16);                          \
    _Pragma("unroll")                                                          \
    for (int nl = 0; nl < 6; ++nl) {                                           \
      const int row = 96 * wc + 16 * nl + l15;                                 \
      _Pragma("unroll")                                                        \
      for (int kk = 0; kk < 2; ++kk)                                           \
        bfr[nl][kk] = *(const s8v*)(Bb + row * 128 +                           \
                       ((kk * 64 + g * 16) ^ ((l15 & 7) << 4)));               \
    }                                                                          \
    __builtin_amdgcn_s_setprio(1);                                             \
    _Pragma("unroll")                                                          \
    for (int kk = 0; kk < 2; ++kk)                                             \
      _Pragma("unroll")                                                        \
      for (int mi = 0; mi < 2; ++mi)                                           \
        _Pragma("unroll")                                                      \
        for (int nl = 0; nl < 6; ++nl)                                         \
          acc[mi * 6 + nl] = __builtin_amdgcn_mfma_f32_16x16x32_bf16(          \
              af[mi][kk], bfr[nl][kk], acc[mi * 6 + nl], 0, 0, 0);             \
    __builtin_amdgcn_s_setprio(0);                                             \
  }

#define PBODY(SEL, K0, XA, XB, DOX, WN)                                        \
  {                                                                            \
    if ((K0) + 64 < 2048) {                                                    \
      STAGE_B(psmem + ((SEL) ^ 1) * 49152, (K0) + 64)                          \
    }                                                                          \
    __builtin_amdgcn_sched_barrier(0);   /* DMAs strictly oldest */            \
    if ((K0) + 64 < 2048) {                                                    \
      WRITE_A(psmem + 98304 + ((SEL) ^ 1) * 9216, XA, XB)                      \
    }                                                                          \
    if (DOX) {                                                                 \
      XA = *(const f4v*)(xsrc + (K0) + 192);                                   \
      XB = *(const f4v*)(xsrc + (K0) + 196);                                   \
    }                                                                          \
    COMPUTE(SEL)                                                               \
    asm volatile("s_waitcnt lgkmcnt(0)" ::: "memory");                         \
    asm volatile("s_waitcnt vmcnt(" #WN ")" ::: "memory");                     \
    __builtin_amdgcn_s_barrier();                                              \
  }

  // prologue: x(0); B(0) [PIN]; x(1); A(0)<-x(0); issue x(2); wait B(0)
  f4v xe_a = *(const f4v*)(xsrc);
  f4v xe_b = *(const f4v*)(xsrc + 4);
  STAGE_B(psmem, 0)
  __builtin_amdgcn_sched_barrier(0);
  f4v xo_a = *(const f4v*)(xsrc + 64);
  f4v xo_b = *(const f4v*)(xsrc + 68);
  WRITE_A(psmem + 98304, xe_a, xe_b)
  xe_a = *(const f4v*)(xsrc + 128);
  xe_b = *(const f4v*)(xsrc + 132);
  asm volatile("s_waitcnt lgkmcnt(0)" ::: "memory");
  asm volatile("s_waitcnt vmcnt(4)" ::: "memory");   // B(0) done; x(1),x(2) fly
  __builtin_amdgcn_s_barrier();

  for (int it = 0; it < 14; ++it) {                  // bodies 0..27 (all full)
    const int k0 = it * 128;
    PBODY(0, k0, xo_a, xo_b, 1, 2)
    PBODY(1, k0 + 64, xe_a, xe_b, 1, 2)
  }
  PBODY(0, 1792, xo_a, xo_b, 1, 2)                   // t28 (loads x31)
  PBODY(1, 1856, xe_a, xe_b, 0, 0)                   // t29
  PBODY(0, 1920, xo_a, xo_b, 0, 0)                   // t30 (stages B31,A31)
  COMPUTE(1)                                         // t31
#undef PBODY
#undef STAGE_B
#undef WRITE_A
#undef COMPUTE

  // ---- epilogue: q,k direct; v -> LDS transpose (scr aliases B0) ----
  #pragma unroll
  for (int mi = 0; mi < 2; ++mi) {
    #pragma unroll
    for (int nl = 0; nl < 6; ++nl) {
      const int colg = 96 * wc + 16 * nl + l15;   // 0..383
      const int m = colg >> 7;                    // 0=q 1=k 2=v
      const int h = colg & 127;
      const f4v a = acc[mi * 6 + nl];
      if (m < 2) {
        unsigned short* dst = (m == 0) ? Qo : Ko;
        #pragma unroll
        for (int r = 0; r < 4; ++r) {
          const int t = rowbase + 32 * wr + 16 * mi + 4 * g + r;
          dst[(size_t)t * 128 + h] = f2bf(a[r]);
        }
      } else {
        #pragma unroll
        for (int r = 0; r < 4; ++r) {
          const int tl = 32 * wr + 16 * mi + 4 * g + r;  // 0..63
          scr[h * 72 + tl] = f2bf(a[r]);
        }
      }
    }
  }
  __syncthreads();
  {
    const int b   = rowbase >> 12;
    const int tg0 = rowbase & 4095;
    const int h    = tid >> 2;                    // 0..127
    const int toff = (tid & 3) * 16;              // 0..48
    unsigned short* dst = VTo + (size_t)(b * 128 + h) * 4096 + tg0 + toff;
    *(s8v*)(dst)     = *(const s8v*)(&scr[h * 72 + toff]);
    *(s8v*)(dst + 8) = *(const s8v*)(&scr[h * 72 + toff + 8]);
  }
}

// ---- attention (exact R9: simple loop + PAIRED map, best measured) ---------
// Block = 4 waves, ONE 32-row q-strip; KV tile 64 DMA-staged to LDS (dbuf,
// XOR-swizzled via pre-swizzled source). SWAPPED MFMA: S^T=mfma(K,Q),
// O^T=mfma(VT,P) -> lane-local softmax. PAIRED strip map: blocks bid and
// bid+256 land on the same CU; {127-j, j} makes per-CU work constant (127
// tiles) — LPT map measured +10us worse (R12 vs R13/R14, 3:1 CU imbalance).
__global__ __launch_bounds__(256, 2) void attn_kernel(
    const unsigned short* __restrict__ Q, const unsigned short* __restrict__ K,
    const unsigned short* __restrict__ VT, float* __restrict__ out)
{
  __shared__ __align__(16) char smem[71168];
  // [0)      KV dbuf: buf c at c*32768: K 16KB, V 16KB  (aliased by o merge)
  // [65536)  plds [4][16*40] bf16   [70656) ml [4][16][2] f32
  unsigned short* plds = (unsigned short*)(smem + 65536);
  float* mlp = (float*)(smem + 70656);

  const int tid  = threadIdx.x;
  const int w    = tid >> 6;
  const int lane = tid & 63;
  const int l15 = lane & 15, g = lane >> 4;

  const int bid = blockIdx.x;
  const int i8  = bid & 255;
  const int j   = i8 >> 2;
  const int s   = (bid < 256) ? (127 - j) : j;   // long+short pair per CU
  const int b   = i8 & 3;                        // batch <-> XCD affinity
  const int qb = s * 32;
  const int roff = (w >> 1) * 16, half = w & 1;
  const int ntiles = (qb + 95) >> 6;

  const char* Kg = (const char*)(K  + (size_t)b * 4096 * 128);
  const char* Vg = (const char*)(VT + (size_t)b * 128 * 4096);
  const unsigned short* Qb = Q + (size_t)b * 4096 * 128;

  s8v qf[4];
  #pragma unroll
  for (int kk = 0; kk < 4; ++kk)
    qf[kk] = *(const s8v*)(Qb + (size_t)(qb + roff + l15) * 128 + kk * 32 + g * 8);

  f4v o[8];
  #pragma unroll
  for (int n = 0; n < 8; ++n) o[n] = (f4v){0.f, 0.f, 0.f, 0.f};
  float mrun = -1e30f, lrun = 0.f;               // per-lane: q-row = l15

  const int off0 = tid * 16;                     // staging: 16B per thread

#define STAGE(Kl_, kvb_)                                                       \
  {                                                                            \
    char* Kl = (Kl_);                                                          \
    _Pragma("unroll")                                                          \
    for (int p = 0; p < 4; ++p) {                                              \
      const int off = off0 + p * 4096;                                         \
      const int ks = off ^ (((off >> 8) & 7) << 4);                            \
      __builtin_amdgcn_global_load_lds(                                        \
        (const __attribute__((address_space(1))) void*)(Kg + (size_t)(kvb_) * 256 + ks), \
        (__attribute__((address_space(3))) void*)(Kl + off), 16, 0, 0);        \
    }                                                                          \
    _Pragma("unroll")                                                          \
    for (int p = 0; p < 4; ++p) {                                              \
      const int off = off0 + p * 4096;                                         \
      const int h = off >> 7;                                                  \
      const int cs = (off & 127) ^ ((h & 7) << 4);                             \
      __builtin_amdgcn_global_load_lds(                                        \
        (const __attribute__((address_space(1))) void*)(Vg + (size_t)h * 8192 + (size_t)(kvb_) * 2 + cs), \
        (__attribute__((address_space(3))) void*)(Kl + 16384 + off), 16, 0, 0); \
    }                                                                          \
  }

  STAGE(smem, 0)
  __syncthreads();

  int cur = 0;
  for (int it = 0; it < ntiles; ++it) {
    const int kvb = it * 64;
    if (it + 1 < ntiles) STAGE(smem + (cur ^ 1) * 32768, kvb + 64)

    const char* Kl = smem + cur * 32768;
    const char* Vl = Kl + 16384;
    s8v kf[2][4];
    #pragma unroll
    for (int t2 = 0; t2 < 2; ++t2) {
      const int row = half * 32 + t2 * 16 + l15;
      #pragma unroll
      for (int kk = 0; kk < 4; ++kk)
        kf[t2][kk] = *(const s8v*)(Kl + ((row * 256 + kk * 64 + g * 16) ^ ((l15 & 7) << 4)));
    }
    s8v vf[8];
    #pragma unroll
    for (int n = 0; n < 8; ++n) {
      const int row = n * 16 + l15;
      vf[n] = *(const s8v*)(Vl + ((row * 128 + half * 64 + g * 16) ^ ((l15 & 7) << 4)));
    }
    // QK^T swapped: lane holds q-row l15, kv-local = 16*t2 + 4*g + r
    f4v sc[2];
    sc[0] = (f4v){0.f, 0.f, 0.f, 0.f};
    sc[1] = (f4v){0.f, 0.f, 0.f, 0.f};
    __builtin_amdgcn_s_setprio(1);
    #pragma unroll
    for (int kk = 0; kk < 4; ++kk) {
      sc[0] = __builtin_amdgcn_mfma_f32_16x16x32_bf16(kf[0][kk], qf[kk], sc[0], 0, 0, 0);
      sc[1] = __builtin_amdgcn_mfma_f32_16x16x32_bf16(kf[1][kk], qf[kk], sc[1], 0, 0, 0);
    }
    __builtin_amdgcn_s_setprio(0);
    // causal mask (diagonal tile only)
    if (it == ntiles - 1) {
      const int qrow = qb + roff + l15;
      #pragma unroll
      for (int t2 = 0; t2 < 2; ++t2)
        #pragma unroll
        for (int r = 0; r < 4; ++r) {
          const int kv = kvb + half * 32 + 16 * t2 + 4 * g + r;
          if (kv > qrow) sc[t2][r] = -1e30f;
        }
    }
    // lane-local online softmax (row = l15; partners at lane^16, lane^32)
    float v = fmaxf(fmaxf(fmaxf(sc[0][0], sc[0][1]), fmaxf(sc[0][2], sc[0][3])),
                    fmaxf(fmaxf(sc[1][0], sc[1][1]), fmaxf(sc[1][2], sc[1][3])));
    v = fmaxf(v, __shfl_xor(v, 16));
    v = fmaxf(v, __shfl_xor(v, 32));
    if (__any(v > mrun + 4.0f)) {                // defer-max (T13)
      const float mnew = fmaxf(mrun, v);
      const float corr = __expf(mrun - mnew);
      mrun = mnew;
      lrun *= corr;
      #pragma unroll
      for (int n = 0; n < 8; ++n)
        #pragma unroll
        for (int r = 0; r < 4; ++r) o[n][r] *= corr;
    }
    f4v p0, p1;
    #pragma unroll
    for (int r = 0; r < 4; ++r) {
      p0[r] = __expf(sc[0][r] - mrun);
      p1[r] = __expf(sc[1][r] - mrun);
    }
    lrun += (p0[0] + p0[1]) + (p0[2] + p0[3]) + (p1[0] + p1[1]) + (p1[2] + p1[3]);
    // P bounce: 4 packed u32 stores -> one b128 A/B-frag read (per-wave buf)
    unsigned short* pw = plds + w * 640;
    *(unsigned int*)(&pw[l15 * 40 + 4 * g])          = pk2bf(p0[0], p0[1]);
    *(unsigned int*)(&pw[l15 * 40 + 4 * g + 2])      = pk2bf(p0[2], p0[3]);
    *(unsigned int*)(&pw[l15 * 40 + 16 + 4 * g])     = pk2bf(p1[0], p1[1]);
    *(unsigned int*)(&pw[l15 * 40 + 16 + 4 * g + 2]) = pk2bf(p1[2], p1[3]);
    const s8v pf = *(const s8v*)(pw + l15 * 40 + g * 8);
    // PV swapped: O^T += VT_frag x P -> lane holds q=l15, h=16n+4g+r
    __builtin_amdgcn_s_setprio(1);
    #pragma unroll
    for (int n = 0; n < 8; ++n)
      o[n] = __builtin_amdgcn_mfma_f32_16x16x32_bf16(vf[n], pf, o[n], 0, 0, 0);
    __builtin_amdgcn_s_setprio(0);

    __syncthreads();                             // drains staging DMA + syncs
    cur ^= 1;
  }
#undef STAGE

  // ---- per-wave finish: l reduce (2 shuffles), dump {m,l,o} partials ----
  float lt = lrun;
  lt += __shfl_xor(lt, 16);
  lt += __shfl_xor(lt, 32);
  if (g == 0) {
    mlp[(w * 16 + l15) * 2 + 0] = mrun;
    mlp[(w * 16 + l15) * 2 + 1] = lt;
  }
  float* ol = (float*)smem;                      // [4][16][132] aliases KV bufs
  #pragma unroll
  for (int n = 0; n < 8; ++n)
    *(f4v*)(&ol[(w * 16 + l15) * 132 + 16 * n + 4 * g]) = o[n];
  __syncthreads();

  // ---- merge the 2 col-halves of each 16-row group ----
  {
    const int st  = tid >> 7;                    // row group 0/1
    const int t7  = tid & 127;
    const int row = t7 >> 3;                     // 0..15
    const int hb  = (t7 & 7) * 16;               // 0..112
    const int wA = 2 * st, wB = 2 * st + 1;
    const float m0 = mlp[(wA * 16 + row) * 2], l0 = mlp[(wA * 16 + row) * 2 + 1];
    const float m1 = mlp[(wB * 16 + row) * 2], l1 = mlp[(wB * 16 + row) * 2 + 1];
    const float M  = fmaxf(m0, m1);
    const float w0 = __expf(m0 - M), w1 = __expf(m1 - M);
    const float inv = 1.0f / (w0 * l0 + w1 * l1);
    float* dst = out + (size_t)(b * 4096 + qb + 16 * st + row) * 128 + hb;
    #pragma unroll
    for (int j4 = 0; j4 < 4; ++j4) {
      const f4v a = *(const f4v*)(&ol[(wA * 16 + row) * 132 + hb + 4 * j4]);
      const f4v c = *(const f4v*)(&ol[(wB * 16 + row) * 132 + hb + 4 * j4]);
      f4v res;
      #pragma unroll
      for (int jj = 0; jj < 4; ++jj) res[jj] = (w0 * a[jj] + w1 * c[jj]) * inv;
      *(f4v*)(dst + 4 * j4) = res;
    }
  }
}

extern "C" void kernel_launch(void* const* d_in, const int* in_sizes, int n_in,
                              void* d_out, int out_size, void* d_ws, size_t ws_size,
                              hipStream_t stream) {
  const float* x  = (const float*)d_in[0];
  const float* Wq = (const float*)d_in[1];
  const float* Wk = (const float*)d_in[2];
  const float* Wv = (const float*)d_in[3];

  unsigned short* WT = (unsigned short*)d_ws;
  unsigned short* Q  = (unsigned short*)((char*)d_ws + 1572864);
  unsigned short* K  = (unsigned short*)((char*)d_ws + 5767168);
  unsigned short* VT = (unsigned short*)((char*)d_ws + 9961472);
  float* out = (float*)d_out;

  prep_wt<<<3072, 256, 0, stream>>>(Wq, Wk, Wv, WT);
  proj_kernel<<<256, 512, 0, stream>>>(x, WT, Q, K, VT);
  attn_kernel<<<512, 256, 0, stream>>>(Q, K, VT, out);
}